// Round 6
// baseline (375.963 us; speedup 1.0000x reference)
//
#include <hip/hip_runtime.h>
#include <hip/hip_bf16.h>
#include <cstdint>
#include <cstddef>

// ---- constants (fixed by the reference problem) ----
#define Hh 1024
#define D_EMB 512
#define D_UP 2048
#define BT 16384      // B*T
#define BB_ 512
#define Mm 4096
#define NB 32         // BT/BB
#define KL 64         // K_LABELS
#define NXCD 8
#define PMMAX 8192    // max padded kv rows (labels padded to 64)
#define QROWMAX 17408 // max padded q rows (labels padded to 16)
#define MAXT 1088     // max (label, qtile16) tasks

typedef __attribute__((ext_vector_type(4))) float f4;
typedef __attribute__((ext_vector_type(4))) __bf16 bf4;
typedef __attribute__((ext_vector_type(8))) __bf16 bf8;
typedef __attribute__((ext_vector_type(4))) float f32x4;

// ---------------- helpers ----------------
__device__ __forceinline__ void gl_lds16(const void* g, void* l) {
  __builtin_amdgcn_global_load_lds((__attribute__((address_space(1))) void*)g,
                                   (__attribute__((address_space(3))) void*)l, 16, 0, 0);
}

// ---------------- prep kernels ----------------
__global__ __launch_bounds__(256) void conv_bf16_kernel(const float* __restrict__ src,
                                                        __bf16* __restrict__ dst, int n4) {
  int i = blockIdx.x * 256 + threadIdx.x;
  if (i >= n4) return;
  f4 v = ((const f4*)src)[i];
  bf4 o = {(__bf16)v[0], (__bf16)v[1], (__bf16)v[2], (__bf16)v[3]};
  ((bf4*)dst)[i] = o;
}

__global__ __launch_bounds__(256) void la_kernel(const int* __restrict__ keep,
                                                 const int* __restrict__ emb,
                                                 int* __restrict__ la, int m) {
  int i = blockIdx.x * 256 + threadIdx.x;
  if (i < m) la[i] = emb[keep[i]];
}

__global__ __launch_bounds__(256) void range_kernel(const int* __restrict__ starts,
                                                    const int* __restrict__ ends,
                                                    int* __restrict__ stA, int* __restrict__ enA) {
  int n = blockIdx.x;
  int t = threadIdx.x, lane = t & 63, wv = t >> 6;
  int s1 = min(starts[n * BB_ + t], starts[n * BB_ + t + 256]);
  int e1 = max(ends[n * BB_ + t], ends[n * BB_ + t + 256]);
#pragma unroll
  for (int off = 32; off; off >>= 1) {
    s1 = min(s1, __shfl_xor(s1, off));
    e1 = max(e1, __shfl_xor(e1, off));
  }
  __shared__ int ssh[4], esh[4];
  if (lane == 0) { ssh[wv] = s1; esh[wv] = e1; }
  __syncthreads();
  if (t == 0) {
    int s = ssh[0], e = esh[0];
#pragma unroll
    for (int k = 1; k < 4; ++k) { s = min(s, ssh[k]); e = max(e, esh[k]); }
    stA[n] = s; enA[n] = e;
  }
}

// histogram of labels over all Mm rows + exclusive prefix -> goff[KL+1]
__global__ __launch_bounds__(256) void hist_kernel(const int* __restrict__ la,
                                                   int* __restrict__ goff) {
  __shared__ int cnt[KL];
  int tid = threadIdx.x;
  if (tid < KL) cnt[tid] = 0;
  __syncthreads();
  for (int k = tid; k < Mm; k += 256) atomicAdd(&cnt[la[k]], 1);
  __syncthreads();
  if (tid == 0) {
    int a = 0;
    for (int s = 0; s < KL; ++s) { goff[s] = a; a += cnt[s]; }
    goff[KL] = a;
  }
}

// stable placement: global sorted-by-(label,k) order. one wg per label.
__global__ __launch_bounds__(256) void place_kernel(const int* __restrict__ la,
                                                    const int* __restrict__ keep,
                                                    const int* __restrict__ goff,
                                                    int* __restrict__ gk,
                                                    int* __restrict__ ridx) {
  int s = blockIdx.x;
  int tid = threadIdx.x, lane = tid & 63, wv = tid >> 6;
  __shared__ int wc[4];
  __shared__ int run;
  if (tid == 0) run = goff[s];
  __syncthreads();
  for (int base = 0; base < Mm; base += 256) {
    int k = base + tid;
    bool f = (la[k] == s);
    unsigned long long msk = __ballot(f);
    int myidx = __popcll(msk & ((1ull << lane) - 1ull));
    if (lane == 0) wc[wv] = __popcll(msk);
    __syncthreads();
    int woff = 0, tot = 0;
#pragma unroll
    for (int w = 0; w < 4; ++w) {
      if (w < wv) woff += wc[w];
      tot += wc[w];
    }
    int rbase = run;
    if (f) {
      int p = rbase + woff + myidx;
      gk[p] = k;
      ridx[p] = keep[k];
    }
    __syncthreads();
    if (tid == 0) run = rbase + tot;
    __syncthreads();
  }
}

// counting sort of queries by label within each block of 512
__global__ __launch_bounds__(256) void qsort_kernel(const int* __restrict__ seq_sort,
                                                    int* __restrict__ qidx,
                                                    int* __restrict__ qoffA,
                                                    int* __restrict__ qcntA) {
  int n = blockIdx.x, tid = threadIdx.x;
  __shared__ int cnt[KL], pos[KL], pref[KL];
  if (tid < KL) cnt[tid] = 0;
  __syncthreads();
  int s0 = seq_sort[n * BB_ + tid];
  int s1 = seq_sort[n * BB_ + tid + 256];
  atomicAdd(&cnt[s0], 1);
  atomicAdd(&cnt[s1], 1);
  __syncthreads();
  if (tid == 0) {
    int a = 0;
    for (int s = 0; s < KL; ++s) { pref[s] = a; a += cnt[s]; }
  }
  __syncthreads();
  if (tid < KL) {
    pos[tid] = pref[tid];
    qoffA[n * KL + tid] = pref[tid];
    qcntA[n * KL + tid] = cnt[tid];
  }
  __syncthreads();
  int p0 = atomicAdd(&pos[s0], 1);
  qidx[n * BB_ + p0] = n * BB_ + tid;
  int p1 = atomicAdd(&pos[s1], 1);
  qidx[n * BB_ + p1] = n * BB_ + tid + 256;
}

// metadata: per-label q prefix over blocks (boff), qtot, padded q-tile base ptq,
// padded kv base pb, task table, counts.
__global__ __launch_bounds__(256) void qmeta_kernel(const int* __restrict__ qcntA,
                                                    const int* __restrict__ goff,
                                                    int* __restrict__ boff,
                                                    int* __restrict__ qtot,
                                                    int* __restrict__ ptq,
                                                    int* __restrict__ pb,
                                                    int* __restrict__ taskS,
                                                    int* __restrict__ taskT,
                                                    int* __restrict__ ntt,
                                                    int* __restrict__ pbTot) {
  int tid = threadIdx.x;
  if (tid < KL) {
    int s = tid, tot = 0;
    for (int n = 0; n < NB; ++n) { boff[n * KL + s] = tot; tot += qcntA[n * KL + s]; }
    qtot[s] = tot;
  }
  __syncthreads();
  if (tid == 0) {
    int tb = 0, tk = 0, pk = 0;
    for (int s = 0; s < KL; ++s) {
      ptq[s] = tb;
      int nt = (qtot[s] + 15) >> 4;
      for (int t2 = 0; t2 < nt; ++t2) { taskS[tk] = s; taskT[tk] = t2; ++tk; }
      tb += nt;
      pb[s] = pk;
      int cnt = goff[s + 1] - goff[s];
      pk += (cnt + 63) & ~63;
    }
    ptq[KL] = tb;
    ntt[0] = tk;
    pbTot[0] = pk;
  }
}

// pridx[p] = source w_k/w_v row for padded pos p (-1 for pad)
__global__ __launch_bounds__(256) void pridx_kernel(const int* __restrict__ goff,
                                                    const int* __restrict__ pb,
                                                    const int* __restrict__ ridx,
                                                    int* __restrict__ pridx) {
  int s = blockIdx.x;
  int cnt = goff[s + 1] - goff[s];
  int padded = (cnt + 63) & ~63;
  int base = pb[s];
  for (int i = threadIdx.x; i < padded; i += 256)
    pridx[base + i] = (i < cnt) ? ridx[goff[s] + i] : -1;
}

// per (block,label): contiguous PADDED sorted-pos range [lo,hi)
__global__ __launch_bounds__(256) void lohi_kernel(const int* __restrict__ gk,
                                                   const int* __restrict__ goff,
                                                   const int* __restrict__ pb,
                                                   const int* __restrict__ stA,
                                                   const int* __restrict__ enA,
                                                   int* __restrict__ loA, int* __restrict__ hiA) {
  int i = blockIdx.x * 256 + threadIdx.x;
  if (i >= NB * KL) return;
  int n = i / KL, s = i % KL;
  int b = goff[s], e = goff[s + 1];
  int st = stA[n], en = enA[n];
  int lo = b, hi = e;
  while (lo < hi) { int mid = (lo + hi) >> 1; if (gk[mid] < st) lo = mid + 1; else hi = mid; }
  int L = lo;
  lo = b; hi = e;
  while (lo < hi) { int mid = (lo + hi) >> 1; if (gk[mid] < en) lo = mid + 1; else hi = mid; }
  loA[i] = pb[s] + (L - goff[s]);
  hiA[i] = pb[s] + (lo - goff[s]);
}

// global label-sorted q order + inverse map
__global__ __launch_bounds__(256) void gq_kernel(const int* __restrict__ qidx,
                                                 const int* __restrict__ qoffA,
                                                 const int* __restrict__ seq_sort,
                                                 const int* __restrict__ boff,
                                                 const int* __restrict__ ptq,
                                                 int* __restrict__ qg2, int* __restrict__ gq) {
  int e = blockIdx.x * 256 + threadIdx.x;
  int n = e >> 9;
  int q = qidx[e];
  int s = seq_sort[q];
  int i = (e & 511) - qoffA[n * KL + s];
  int gpos = ptq[s] * 16 + boff[n * KL + s] + i;
  qg2[gpos] = q;
  gq[q] = gpos;
}

// zero the label-tail pad rows of Qsw (deterministic each launch)
__global__ __launch_bounds__(256) void qzero_kernel(const int* __restrict__ ptq,
                                                    const int* __restrict__ qtot,
                                                    __bf16* __restrict__ Qsw) {
  int s = blockIdx.x;
  int b0 = ptq[s] * 16 + qtot[s];
  int b1 = ptq[s + 1] * 16;
  bf8 z;
#pragma unroll
  for (int j = 0; j < 8; ++j) z[j] = (__bf16)0.f;
  for (int r = b0; r < b1; ++r)
    for (int e8 = threadIdx.x; e8 < 128; e8 += 256)
      *(bf8*)&Qsw[(size_t)r * 1024 + e8 * 8] = z;
}

// Ksw[pt][ks][lane][8] = K[pt*16 + (lane&15)][ks*32 + (lane>>4)*8 + i] (bf16; pad rows zero)
__global__ __launch_bounds__(256) void kswb_kernel(const float* __restrict__ wk,
                                                   const int* __restrict__ pridx,
                                                   const int* __restrict__ pbTot,
                                                   __bf16* __restrict__ Ksw) {
  int pt = blockIdx.x;
  if (pt * 16 >= pbTot[0]) return;
  __shared__ __bf16 Tk[16][1040];
  int tid = threadIdx.x;
  int rr = tid >> 4, lt = tid & 15;
  int src = pridx[pt * 16 + rr];
  for (int cc = 0; cc < 16; ++cc) {
    int i4 = cc * 16 + lt;
    f4 v = {0.f, 0.f, 0.f, 0.f};
    if (src >= 0) v = ((const f4*)(wk + (size_t)src * Hh))[i4];
    bf4 o = {(__bf16)v[0], (__bf16)v[1], (__bf16)v[2], (__bf16)v[3]};
    *(bf4*)&Tk[rr][i4 * 4] = o;
  }
  __syncthreads();
#pragma unroll
  for (int i = 0; i < 8; ++i) {
    int f = tid + 256 * i;
    int ks = f >> 6, ln = f & 63;
    int c2 = ln & 15, rg2 = ln >> 4;
    bf8 o = *(const bf8*)&Tk[c2][ks * 32 + rg2 * 8];
    *(bf8*)&Ksw[(size_t)pt * 16384 + (size_t)f * 8] = o;
  }
}

// Vsw[pblk][ff][lane][8] = V^T[ff*16 + (lane&15)][pblk*32 + (lane>>4)*8 + i]
__global__ __launch_bounds__(256) void vswb_kernel(const float* __restrict__ wv_,
                                                   const int* __restrict__ pridx,
                                                   const int* __restrict__ pbTot,
                                                   __bf16* __restrict__ Vsw) {
  int pblk = blockIdx.x;
  if (pblk * 32 >= pbTot[0]) return;
  __shared__ __bf16 Tv[32][528];
  int tid = threadIdx.x;
  int rr = tid >> 3, lt = tid & 7;
  int src = pridx[pblk * 32 + rr];
  for (int cc = 0; cc < 16; ++cc) {
    int i4 = cc * 8 + lt;
    f4 v = {0.f, 0.f, 0.f, 0.f};
    if (src >= 0) v = ((const f4*)(wv_ + (size_t)src * D_EMB))[i4];
    bf4 o = {(__bf16)v[0], (__bf16)v[1], (__bf16)v[2], (__bf16)v[3]};
    *(bf4*)&Tv[rr][i4 * 4] = o;
  }
  __syncthreads();
#pragma unroll
  for (int i = 0; i < 8; ++i) {
    int f = tid + 256 * i;
    int ff = f >> 6, ln = f & 63;
    int c2 = ln & 15, rg2 = ln >> 4;
    bf8 o;
#pragma unroll
    for (int j = 0; j < 8; ++j) o[j] = Tv[rg2 * 8 + j][ff * 16 + c2];
    *(bf8*)&Vsw[(size_t)pblk * 16384 + (size_t)f * 8] = o;
  }
}

// ---------------- RMSNorm of input: inb[j] = bf16(input[j]); Qsw row gq[bw[j]] ----------------
__global__ __launch_bounds__(256) void rms_in_kernel(const float* __restrict__ input,
                                                     const int* __restrict__ bw,
                                                     const int* __restrict__ gq,
                                                     const float* __restrict__ wn,
                                                     __bf16* __restrict__ Qsw,
                                                     __bf16* __restrict__ inb) {
  __shared__ __align__(16) __bf16 rowbuf[4][1024];
  int wv = threadIdx.x >> 6, lane = threadIdx.x & 63;
  int j = blockIdx.x * 4 + wv;
  const f4* src = (const f4*)(input + (size_t)j * Hh);
  f4 v[4];
  float ss = 0.f;
#pragma unroll
  for (int c = 0; c < 4; ++c) {
    v[c] = src[c * 64 + lane];
    ss += v[c][0] * v[c][0] + v[c][1] * v[c][1] + v[c][2] * v[c][2] + v[c][3] * v[c][3];
  }
#pragma unroll
  for (int off = 32; off; off >>= 1) ss += __shfl_xor(ss, off);
  float sc = rsqrtf(ss * (1.f / Hh) + 1e-6f);
  bf4* dstI = (bf4*)(inb + (size_t)j * Hh);
#pragma unroll
  for (int c = 0; c < 4; ++c) {
    bf4 o = {(__bf16)v[c][0], (__bf16)v[c][1], (__bf16)v[c][2], (__bf16)v[c][3]};
    dstI[c * 64 + lane] = o;
  }
  const f4* w4 = (const f4*)wn;
#pragma unroll
  for (int c = 0; c < 4; ++c) {
    f4 w = w4[c * 64 + lane];
    bf4 o = {(__bf16)(v[c][0] * sc * w[0]), (__bf16)(v[c][1] * sc * w[1]),
             (__bf16)(v[c][2] * sc * w[2]), (__bf16)(v[c][3] * sc * w[3])};
    *(bf4*)&rowbuf[wv][(c * 64 + lane) * 4] = o;
  }
  int gpos = gq[bw[j]];
  int qt2 = gpos >> 4, cq = gpos & 15;
#pragma unroll
  for (int h = 0; h < 2; ++h) {
    int k_ = lane + h * 64;
    int ks = k_ >> 2, rg2 = k_ & 3;
    bf8 o = *(const bf8*)&rowbuf[wv][ks * 32 + rg2 * 8];
    *(bf8*)(Qsw + (size_t)qt2 * 16384 + ks * 512 + (cq + 16 * rg2) * 8) = o;
  }
}

// ---------------- wave-per-(label,qtile16) attention, fragment-major operands ----------------
__global__ __launch_bounds__(256, 2) void attn5_kernel(const __bf16* __restrict__ Qsw,
                                                       const __bf16* __restrict__ Ksw,
                                                       const __bf16* __restrict__ Vsw,
                                                       const int* __restrict__ qg2,
                                                       const int* __restrict__ qtot,
                                                       const int* __restrict__ ptq,
                                                       const int* __restrict__ taskS,
                                                       const int* __restrict__ taskT,
                                                       const int* __restrict__ nttA,
                                                       const int* __restrict__ pb,
                                                       const int* __restrict__ loP,
                                                       const int* __restrict__ hiP,
                                                       const int* __restrict__ fw,
                                                       __bf16* __restrict__ comb) {
  __shared__ __align__(16) __bf16 owb[4][16][528];
  int wv = threadIdx.x >> 6, lane = threadIdx.x & 63;
  int t = blockIdx.x * 4 + wv;
  if (t >= nttA[0]) return;
  int s = taskS[t], tl = taskT[t];
  int qtp = ptq[s] + tl;
  int qcnt = min(16, qtot[s] - tl * 16);
  int c = lane & 15, rg = lane >> 4;
  bool qv = c < qcnt;
  int q_l = qg2[qtp * 16 + (qv ? c : 0)];
  int n_l = q_l >> 9;
  int lo_l = qv ? loP[n_l * KL + s] : 0x7fffffff;
  int hi_l = qv ? hiP[n_l * KL + s] : 0;
  int tlo = lo_l, thi = hi_l;
#pragma unroll
  for (int off = 1; off < 64; off <<= 1) {
    tlo = min(tlo, __shfl_xor(tlo, off));
    thi = max(thi, __shfl_xor(thi, off));
  }
  if (tlo >= thi) return;
  int pbs = pb[s];

  int sl_a = c + ((rg & 1) << 5);
  int sl_b = sl_a + 16;
  bool hiKt = (rg & 2) != 0;
  const __bf16* Qb = Qsw + (size_t)qtp * 16384 + lane * 8;

  float m = -1e30f, lsum = 0.f;
  f32x4 acc[32];
  f32x4 zero = {0.f, 0.f, 0.f, 0.f};
#pragma unroll
  for (int ff = 0; ff < 32; ++ff) acc[ff] = zero;

  int p0beg = pbs + ((tlo - pbs) & ~63);
  for (int p0 = p0beg; p0 < thi; p0 += 64) {
    const __bf16* Kb = Ksw + (size_t)(p0 >> 4) * 16384 + lane * 8;
    f32x4 sN[4];
#pragma unroll
    for (int kt = 0; kt < 4; ++kt) sN[kt] = zero;
#pragma unroll
    for (int ks = 0; ks < 32; ++ks) {
      bf8 qf = *(const bf8*)(Qb + ks * 512);
#pragma unroll
      for (int kt = 0; kt < 4; ++kt) {
        bf8 kf = *(const bf8*)(Kb + kt * 16384 + ks * 512);
        sN[kt] = __builtin_amdgcn_mfma_f32_16x16x32_bf16(kf, qf, sN[kt], 0, 0, 0);
      }
    }
    // mask + per-lane online softmax (lane owns q=c; rows kv)
    float smax = -1e30f;
#pragma unroll
    for (int kt = 0; kt < 4; ++kt)
#pragma unroll
      for (int r = 0; r < 4; ++r) {
        int kv = p0 + kt * 16 + rg * 4 + r;
        float sv = (kv >= lo_l && kv < hi_l) ? sN[kt][r] : -1e30f;
        sN[kt][r] = sv;
        smax = fmaxf(smax, sv);
      }
    smax = fmaxf(smax, __shfl_xor(smax, 16));
    smax = fmaxf(smax, __shfl_xor(smax, 32));
    float mn = fmaxf(m, smax);
    float scl = __expf(m - mn);
    float sum = 0.f;
#pragma unroll
    for (int kt = 0; kt < 4; ++kt)
#pragma unroll
      for (int r = 0; r < 4; ++r) {
        float pv = __expf(sN[kt][r] - mn);
        sN[kt][r] = pv;
        sum += pv;
      }
    sum += __shfl_xor(sum, 16);
    sum += __shfl_xor(sum, 32);
    lsum = lsum * scl + sum;
    m = mn;
#pragma unroll
    for (int ff = 0; ff < 32; ++ff) acc[ff] = acc[ff] * scl;

    // repack P to PV B-frags (proven attn4 math)
    bf8 pbh[2];
#pragma unroll
    for (int h = 0; h < 2; ++h) {
      float e[8];
#pragma unroll
      for (int r = 0; r < 4; ++r) {
        float a0 = __shfl(sN[2 * h][r], sl_a);
        float a1 = __shfl(sN[2 * h + 1][r], sl_a);
        e[r] = hiKt ? a1 : a0;
        float b0 = __shfl(sN[2 * h][r], sl_b);
        float b1 = __shfl(sN[2 * h + 1][r], sl_b);
        e[4 + r] = hiKt ? b1 : b0;
      }
      bf8 pbv;
#pragma unroll
      for (int i = 0; i < 8; ++i) pbv[i] = (__bf16)e[i];
      pbh[h] = pbv;
    }
    // PV: coalesced Vsw frag loads
    const __bf16* Vb = Vsw + (size_t)(p0 >> 5) * 16384 + lane * 8;
#pragma unroll
    for (int ff = 0; ff < 32; ++ff) {
      bf8 v0 = *(const bf8*)(Vb + ff * 512);
      bf8 v1 = *(const bf8*)(Vb + 16384 + ff * 512);
      acc[ff] = __builtin_amdgcn_mfma_f32_16x16x32_bf16(v0, pbh[0], acc[ff], 0, 0, 0);
      acc[ff] = __builtin_amdgcn_mfma_f32_16x16x32_bf16(v1, pbh[1], acc[ff], 0, 0, 0);
    }
  }

  // epilogue: normalize, per-wave LDS transpose, coalesced store
  float inv = 1.f / lsum;
#pragma unroll
  for (int ff = 0; ff < 32; ++ff) {
    bf4 o;
#pragma unroll
    for (int r = 0; r < 4; ++r) o[r] = (__bf16)(acc[ff][r] * inv);
    *(bf4*)&owb[wv][c][ff * 16 + rg * 4] = o;
  }
  int qsel = lane >> 2;
  bool vq = qsel < qcnt;
  size_t ob = 0;
  if (vq) ob = (size_t)fw[qg2[qtp * 16 + qsel]] * D_EMB + (lane & 3) * 8;
#pragma unroll
  for (int it = 0; it < 16; ++it) {
    bf8 o = *(const bf8*)&owb[wv][lane >> 2][(lane & 3) * 8 + it * 32];
    if (vq) *(bf8*)(comb + ob + (size_t)it * 32) = o;
  }
}

// ---------------- 256x256 phase-pipelined GEMM: C = X @ W^T ----------------
template <bool OUT_BF16>
__global__ __launch_bounds__(512, 2) void gemm8p(const __bf16* __restrict__ x0, int k0,
                                                 const __bf16* __restrict__ x1, int k1,
                                                 const __bf16* __restrict__ w,
                                                 void* __restrict__ outp, int Mt, int Nt) {
  __shared__ __align__(16) __bf16 lds[4][2][256 * 32];
  const int nwg = Mt * Nt;
  const int bid = blockIdx.x;
  const int swz = (bid % NXCD) * (nwg / NXCD) + bid / NXCD;
  const int m0 = (swz / Nt) * 256, n0 = (swz % Nt) * 256;
  const int K = k0 + k1;
  const int NT = K >> 5;
  const int N = Nt * 256;
  const int tid = threadIdx.x, lane = tid & 63, wvi = tid >> 6;
  const int wr = wvi >> 2, wc = wvi & 3;

  const int srow = tid >> 2;
  const int spb = (tid & 3) * 16;

  const int c = lane & 15, rg = lane >> 4;
  const int fa_off = c * 64 + ((rg ^ ((c >> 1) & 3)) << 4);

  auto stage_half = [&](int t, int j) {
    int kg = t * 32;
    const __bf16* xs;
    int ld, kk;
    if (kg < k0) { xs = x0; ld = k0; kk = kg; }
    else         { xs = x1; ld = k1; kk = kg - k0; }
    int b = t & 3;
    int r = j * 128 + srow;
    int lcol = (spb ^ (((r >> 1) & 3) << 4)) >> 1;
    gl_lds16(xs + (size_t)(m0 + r) * ld + kk + lcol,
             (void*)((char*)&lds[b][0][0] + r * 64 + spb));
    gl_lds16(w + (size_t)(n0 + r) * K + kg + lcol,
             (void*)((char*)&lds[b][1][0] + r * 64 + spb));
  };

  f32x4 acc[8][4];
  f32x4 zero = {0.f, 0.f, 0.f, 0.f};
#pragma unroll
  for (int a = 0; a < 8; ++a)
#pragma unroll
    for (int bnx = 0; bnx < 4; ++bnx) acc[a][bnx] = zero;

#pragma unroll
  for (int t = 0; t < 3; ++t) {
    stage_half(t, 0);
    stage_half(t, 1);
  }
  asm volatile("s_waitcnt vmcnt(8)" ::: "memory");
  __builtin_amdgcn_s_barrier();

  for (int t = 0; t < NT; ++t) {
    const char* Abase = (const char*)&lds[t & 3][0][0];
    const char* Bbase = (const char*)&lds[t & 3][1][0];
    bf8 bfr[4];
#pragma unroll
    for (int ri = 0; ri < 2; ++ri) {
      if (t + 3 < NT) stage_half(t + 3, ri);
      bf8 afr[4];
#pragma unroll
      for (int fi = 0; fi < 4; ++fi)
        afr[fi] = *(const bf8*)(Abase + (wr * 128 + ri * 64 + fi * 16) * 64 + fa_off);
      if (ri == 0) {
#pragma unroll
        for (int fi = 0; fi < 4; ++fi)
          bfr[fi] = *(const bf8*)(Bbase + (wc * 64 + fi * 16) * 64 + fa_off);
      }
      __builtin_amdgcn_s_barrier();
      __builtin_amdgcn_s_setprio(1);
#pragma unroll
      for (int fi = 0; fi < 4; ++fi)
#pragma unroll
        for (int ni = 0; ni < 4; ++ni)
          acc[ri * 4 + fi][ni] =
              __builtin_amdgcn_mfma_f32_16x16x32_bf16(afr[fi], bfr[ni], acc[ri * 4 + fi][ni], 0, 0, 0);
      __builtin_amdgcn_s_setprio(0);
      if (ri == 1) asm volatile("s_waitcnt vmcnt(8)" ::: "memory");
      __builtin_amdgcn_s_barrier();
    }
  }

  const int r0 = (lane >> 4) * 4, cc = lane & 15;
#pragma unroll
  for (int mi = 0; mi < 8; ++mi) {
    int rowb = m0 + wr * 128 + (mi >> 2) * 64 + (mi & 3) * 16 + r0;
#pragma unroll
    for (int ni = 0; ni < 4; ++ni) {
      int col = n0 + wc * 64 + ni * 16 + cc;
#pragma unroll
      for (int r = 0; r < 4; ++r) {
        float v = acc[mi][ni][r];
        if (OUT_BF16)
          ((__bf16*)outp)[(size_t)(rowb + r) * N + col] = (__bf16)v;
        else
          ((float*)outp)[(size_t)(rowb + r) * N + col] = v;
      }
    }
  }
}

// ---------------- in-place RMSNorm of up ----------------
__global__ __launch_bounds__(256) void rms_up_kernel(__bf16* __restrict__ up,
                                                     const float* __restrict__ wn) {
  int wv = threadIdx.x >> 6, lane = threadIdx.x & 63;
  size_t j = (size_t)blockIdx.x * 4 + wv;
  bf8* row = (bf8*)(up + j * D_UP);
  bf8 v[4];
  float ss = 0.f;
#pragma unroll
  for (int c = 0; c < 4; ++c) {
    v[c] = row[c * 64 + lane];
#pragma unroll
    for (int i = 0; i < 8; ++i) { float f = (float)v[c][i]; ss += f * f; }
  }
#pragma unroll
  for (int off = 32; off; off >>= 1) ss += __shfl_xor(ss, off);
  float sc = rsqrtf(ss * (1.f / D_UP) + 1e-6f);
#pragma unroll
  for (int c = 0; c < 4; ++c) {
    int ebase = (c * 64 + lane) * 8;
    f4 wa = *(const f4*)(wn + ebase);
    f4 wb = *(const f4*)(wn + ebase + 4);
    bf8 o;
#pragma unroll
    for (int i = 0; i < 4; ++i) o[i] = (__bf16)((float)v[c][i] * sc * wa[i]);
#pragma unroll
    for (int i = 0; i < 4; ++i) o[4 + i] = (__bf16)((float)v[c][4 + i] * sc * wb[i]);
    row[c * 64 + lane] = o;
  }
}

// ---------------- launch ----------------
extern "C" void kernel_launch(void* const* d_in, const int* in_sizes, int n_in, void* d_out,
                              int out_size, void* d_ws, size_t ws_size, hipStream_t stream) {
  const float* input = (const float*)d_in[0];
  const int* fw = (const int*)d_in[1];
  const int* bw = (const int*)d_in[2];
  const int* seq_sort = (const int*)d_in[3];
  const int* keep_cols = (const int*)d_in[4];
  const int* emb_alloc = (const int*)d_in[5];
  const int* starts = (const int*)d_in[6];
  const int* ends = (const int*)d_in[7];
  const float* w_k = (const float*)d_in[9];
  const float* w_v = (const float*)d_in[10];
  const float* w_up = (const float*)d_in[11];
  const float* w_mix = (const float*)d_in[12];
  const float* w_nin = (const float*)d_in[13];
  const float* w_nout = (const float*)d_in[14];

  char* p = (char*)d_ws;
  auto take = [&](size_t b) {
    void* r = (void*)p;
    p += (b + 255) & ~(size_t)255;
    return r;
  };
  // region A: persistent through the whole pipeline
  __bf16* inb = (__bf16*)take((size_t)BT * Hh * 2);
  __bf16* comb = (__bf16*)take((size_t)BT * D_EMB * 2);
  __bf16* wupB = (__bf16*)take((size_t)D_UP * D_EMB * 2);
  __bf16* wmixB = (__bf16*)take((size_t)Hh * (D_UP + Hh) * 2);
  // region B: attention-phase only; `up` aliases it afterwards
  char* pB = p;
  __bf16* Ksw = (__bf16*)take((size_t)PMMAX * 1024 * 2);
  __bf16* Vsw = (__bf16*)take((size_t)PMMAX * 512 * 2);
  __bf16* Qsw = (__bf16*)take((size_t)QROWMAX * 1024 * 2);
  int* la = (int*)take(Mm * 4);
  int* stA = (int*)take(NB * 4);
  int* enA = (int*)take(NB * 4);
  int* goff = (int*)take((KL + 1) * 4);
  int* gk = (int*)take(Mm * 4);
  int* ridx = (int*)take(Mm * 4);
  int* pridx = (int*)take(PMMAX * 4);
  int* loA = (int*)take(NB * KL * 4);
  int* hiA = (int*)take(NB * KL * 4);
  int* qidx = (int*)take(BT * 4);
  int* qoffA = (int*)take(NB * KL * 4);
  int* qcntA = (int*)take(NB * KL * 4);
  int* boff = (int*)take(NB * KL * 4);
  int* qtot = (int*)take(KL * 4);
  int* ptq = (int*)take((KL + 1) * 4);
  int* pb = (int*)take(KL * 4);
  int* taskS = (int*)take(MAXT * 4);
  int* taskT = (int*)take(MAXT * 4);
  int* ntt = (int*)take(4);
  int* pbTot = (int*)take(4);
  int* qg2 = (int*)take(QROWMAX * 4);
  int* gq = (int*)take(BT * 4);
  // up aliases region B (dead after attn5); regenerated every launch
  __bf16* up = (__bf16*)pB;

  // prep
  conv_bf16_kernel<<<(D_UP * D_EMB / 4 + 255) / 256, 256, 0, stream>>>(w_up, wupB, D_UP * D_EMB / 4);
  conv_bf16_kernel<<<(Hh * (D_UP + Hh) / 4 + 255) / 256, 256, 0, stream>>>(w_mix, wmixB,
                                                                           Hh * (D_UP + Hh) / 4);
  la_kernel<<<Mm / 256, 256, 0, stream>>>(keep_cols, emb_alloc, la, Mm);
  range_kernel<<<NB, 256, 0, stream>>>(starts, ends, stA, enA);
  hist_kernel<<<1, 256, 0, stream>>>(la, goff);
  qsort_kernel<<<NB, 256, 0, stream>>>(seq_sort, qidx, qoffA, qcntA);
  place_kernel<<<KL, 256, 0, stream>>>(la, keep_cols, goff, gk, ridx);
  qmeta_kernel<<<1, 256, 0, stream>>>(qcntA, goff, boff, qtot, ptq, pb, taskS, taskT, ntt, pbTot);
  pridx_kernel<<<KL, 256, 0, stream>>>(goff, pb, ridx, pridx);
  lohi_kernel<<<(NB * KL + 255) / 256, 256, 0, stream>>>(gk, goff, pb, stA, enA, loA, hiA);
  gq_kernel<<<BT / 256, 256, 0, stream>>>(qidx, qoffA, seq_sort, boff, ptq, qg2, gq);
  qzero_kernel<<<KL, 256, 0, stream>>>(ptq, qtot, Qsw);
  kswb_kernel<<<PMMAX / 16, 256, 0, stream>>>(w_k, pridx, pbTot, Ksw);
  vswb_kernel<<<PMMAX / 32, 256, 0, stream>>>(w_v, pridx, pbTot, Vsw);

  // pipeline
  rms_in_kernel<<<BT / 4, 256, 0, stream>>>(input, bw, gq, w_nin, Qsw, inb);
  attn5_kernel<<<MAXT / 4, 256, 0, stream>>>(Qsw, Ksw, Vsw, qg2, qtot, ptq, taskS, taskT, ntt, pb,
                                             loA, hiA, fw, comb);
  gemm8p<true><<<BT / 256 * (D_UP / 256), 512, 0, stream>>>(comb, D_EMB, (const __bf16*)nullptr, 0,
                                                            wupB, (void*)up, BT / 256, D_UP / 256);
  rms_up_kernel<<<BT / 4, 256, 0, stream>>>(up, w_nout);
  gemm8p<false><<<BT / 256 * (Hh / 256), 512, 0, stream>>>(up, D_UP, inb, Hh, wmixB, d_out,
                                                           BT / 256, Hh / 256);
}

// Round 7
// 365.724 us; speedup vs baseline: 1.0280x; 1.0280x over previous
//
#include <hip/hip_runtime.h>
#include <hip/hip_bf16.h>
#include <cstdint>
#include <cstddef>

// ---- constants (fixed by the reference problem) ----
#define Hh 1024
#define D_EMB 512
#define D_UP 2048
#define BT 16384      // B*T
#define BB_ 512
#define Mm 4096
#define NB 32         // BT/BB
#define KL 64         // K_LABELS
#define NXCD 8
#define PMMAX 8192    // max padded kv rows (labels padded to 64)
#define QROWMAX 17408 // max padded q rows (labels padded to 16)
#define MAXT 1088     // max (label, qtile16) tasks

typedef __attribute__((ext_vector_type(4))) float f4;
typedef __attribute__((ext_vector_type(4))) __bf16 bf4;
typedef __attribute__((ext_vector_type(8))) __bf16 bf8;
typedef __attribute__((ext_vector_type(4))) float f32x4;

// ---------------- helpers ----------------
__device__ __forceinline__ void gl_lds16(const void* g, void* l) {
  __builtin_amdgcn_global_load_lds((__attribute__((address_space(1))) void*)g,
                                   (__attribute__((address_space(3))) void*)l, 16, 0, 0);
}

// ---------------- prep kernels ----------------
__global__ __launch_bounds__(256) void conv_bf16_kernel(const float* __restrict__ src,
                                                        __bf16* __restrict__ dst, int n4) {
  int i = blockIdx.x * 256 + threadIdx.x;
  if (i >= n4) return;
  f4 v = ((const f4*)src)[i];
  bf4 o = {(__bf16)v[0], (__bf16)v[1], (__bf16)v[2], (__bf16)v[3]};
  ((bf4*)dst)[i] = o;
}

__global__ __launch_bounds__(256) void la_kernel(const int* __restrict__ keep,
                                                 const int* __restrict__ emb,
                                                 int* __restrict__ la, int m) {
  int i = blockIdx.x * 256 + threadIdx.x;
  if (i < m) la[i] = emb[keep[i]];
}

__global__ __launch_bounds__(256) void range_kernel(const int* __restrict__ starts,
                                                    const int* __restrict__ ends,
                                                    int* __restrict__ stA, int* __restrict__ enA) {
  int n = blockIdx.x;
  int t = threadIdx.x, lane = t & 63, wv = t >> 6;
  int s1 = min(starts[n * BB_ + t], starts[n * BB_ + t + 256]);
  int e1 = max(ends[n * BB_ + t], ends[n * BB_ + t + 256]);
#pragma unroll
  for (int off = 32; off; off >>= 1) {
    s1 = min(s1, __shfl_xor(s1, off));
    e1 = max(e1, __shfl_xor(e1, off));
  }
  __shared__ int ssh[4], esh[4];
  if (lane == 0) { ssh[wv] = s1; esh[wv] = e1; }
  __syncthreads();
  if (t == 0) {
    int s = ssh[0], e = esh[0];
#pragma unroll
    for (int k = 1; k < 4; ++k) { s = min(s, ssh[k]); e = max(e, esh[k]); }
    stA[n] = s; enA[n] = e;
  }
}

// histogram of labels over all Mm rows + exclusive prefix -> goff[KL+1]
__global__ __launch_bounds__(256) void hist_kernel(const int* __restrict__ la,
                                                   int* __restrict__ goff) {
  __shared__ int cnt[KL];
  int tid = threadIdx.x;
  if (tid < KL) cnt[tid] = 0;
  __syncthreads();
  for (int k = tid; k < Mm; k += 256) atomicAdd(&cnt[la[k]], 1);
  __syncthreads();
  if (tid == 0) {
    int a = 0;
    for (int s = 0; s < KL; ++s) { goff[s] = a; a += cnt[s]; }
    goff[KL] = a;
  }
}

// stable placement: global sorted-by-(label,k) order. one wg per label.
__global__ __launch_bounds__(256) void place_kernel(const int* __restrict__ la,
                                                    const int* __restrict__ keep,
                                                    const int* __restrict__ goff,
                                                    int* __restrict__ gk,
                                                    int* __restrict__ ridx) {
  int s = blockIdx.x;
  int tid = threadIdx.x, lane = tid & 63, wv = tid >> 6;
  __shared__ int wc[4];
  __shared__ int run;
  if (tid == 0) run = goff[s];
  __syncthreads();
  for (int base = 0; base < Mm; base += 256) {
    int k = base + tid;
    bool f = (la[k] == s);
    unsigned long long msk = __ballot(f);
    int myidx = __popcll(msk & ((1ull << lane) - 1ull));
    if (lane == 0) wc[wv] = __popcll(msk);
    __syncthreads();
    int woff = 0, tot = 0;
#pragma unroll
    for (int w = 0; w < 4; ++w) {
      if (w < wv) woff += wc[w];
      tot += wc[w];
    }
    int rbase = run;
    if (f) {
      int p = rbase + woff + myidx;
      gk[p] = k;
      ridx[p] = keep[k];
    }
    __syncthreads();
    if (tid == 0) run = rbase + tot;
    __syncthreads();
  }
}

// counting sort of queries by label within each block of 512
__global__ __launch_bounds__(256) void qsort_kernel(const int* __restrict__ seq_sort,
                                                    int* __restrict__ qidx,
                                                    int* __restrict__ qoffA,
                                                    int* __restrict__ qcntA) {
  int n = blockIdx.x, tid = threadIdx.x;
  __shared__ int cnt[KL], pos[KL], pref[KL];
  if (tid < KL) cnt[tid] = 0;
  __syncthreads();
  int s0 = seq_sort[n * BB_ + tid];
  int s1 = seq_sort[n * BB_ + tid + 256];
  atomicAdd(&cnt[s0], 1);
  atomicAdd(&cnt[s1], 1);
  __syncthreads();
  if (tid == 0) {
    int a = 0;
    for (int s = 0; s < KL; ++s) { pref[s] = a; a += cnt[s]; }
  }
  __syncthreads();
  if (tid < KL) {
    pos[tid] = pref[tid];
    qoffA[n * KL + tid] = pref[tid];
    qcntA[n * KL + tid] = cnt[tid];
  }
  __syncthreads();
  int p0 = atomicAdd(&pos[s0], 1);
  qidx[n * BB_ + p0] = n * BB_ + tid;
  int p1 = atomicAdd(&pos[s1], 1);
  qidx[n * BB_ + p1] = n * BB_ + tid + 256;
}

// metadata: boff/qtot/ptq/pb + XCD-affine task list (tasks ordered by (s%8, s, tile))
__global__ __launch_bounds__(256) void qmeta_kernel(const int* __restrict__ qcntA,
                                                    const int* __restrict__ goff,
                                                    int* __restrict__ boff,
                                                    int* __restrict__ qtot,
                                                    int* __restrict__ ptq,
                                                    int* __restrict__ pb,
                                                    int* __restrict__ taskS,
                                                    int* __restrict__ taskT,
                                                    int* __restrict__ xoff,
                                                    int* __restrict__ xcnt,
                                                    int* __restrict__ pbTot) {
  int tid = threadIdx.x;
  if (tid < KL) {
    int s = tid, tot = 0;
    for (int n = 0; n < NB; ++n) { boff[n * KL + s] = tot; tot += qcntA[n * KL + s]; }
    qtot[s] = tot;
  }
  __syncthreads();
  if (tid == 0) {
    int tb = 0, pk = 0;
    for (int s = 0; s < KL; ++s) {
      ptq[s] = tb;
      tb += (qtot[s] + 15) >> 4;
      pb[s] = pk;
      int cnt = goff[s + 1] - goff[s];
      pk += (cnt + 63) & ~63;
    }
    ptq[KL] = tb;
    pbTot[0] = pk;
    // task list grouped by XCD (= label & 7)
    int tk = 0;
    for (int x = 0; x < NXCD; ++x) {
      xoff[x] = tk;
      for (int s = x; s < KL; s += NXCD) {
        int nt = (qtot[s] + 15) >> 4;
        for (int t2 = 0; t2 < nt; ++t2) { taskS[tk] = s; taskT[tk] = t2; ++tk; }
      }
      xcnt[x] = tk - xoff[x];
    }
  }
}

// pridx[p] = source w_k/w_v row for padded pos p (-1 for pad)
__global__ __launch_bounds__(256) void pridx_kernel(const int* __restrict__ goff,
                                                    const int* __restrict__ pb,
                                                    const int* __restrict__ ridx,
                                                    int* __restrict__ pridx) {
  int s = blockIdx.x;
  int cnt = goff[s + 1] - goff[s];
  int padded = (cnt + 63) & ~63;
  int base = pb[s];
  for (int i = threadIdx.x; i < padded; i += 256)
    pridx[base + i] = (i < cnt) ? ridx[goff[s] + i] : -1;
}

// per (block,label): contiguous PADDED sorted-pos range [lo,hi)
__global__ __launch_bounds__(256) void lohi_kernel(const int* __restrict__ gk,
                                                   const int* __restrict__ goff,
                                                   const int* __restrict__ pb,
                                                   const int* __restrict__ stA,
                                                   const int* __restrict__ enA,
                                                   int* __restrict__ loA, int* __restrict__ hiA) {
  int i = blockIdx.x * 256 + threadIdx.x;
  if (i >= NB * KL) return;
  int n = i / KL, s = i % KL;
  int b = goff[s], e = goff[s + 1];
  int st = stA[n], en = enA[n];
  int lo = b, hi = e;
  while (lo < hi) { int mid = (lo + hi) >> 1; if (gk[mid] < st) lo = mid + 1; else hi = mid; }
  int L = lo;
  lo = b; hi = e;
  while (lo < hi) { int mid = (lo + hi) >> 1; if (gk[mid] < en) lo = mid + 1; else hi = mid; }
  loA[i] = pb[s] + (L - goff[s]);
  hiA[i] = pb[s] + (lo - goff[s]);
}

// global label-sorted q order + inverse map
__global__ __launch_bounds__(256) void gq_kernel(const int* __restrict__ qidx,
                                                 const int* __restrict__ qoffA,
                                                 const int* __restrict__ seq_sort,
                                                 const int* __restrict__ boff,
                                                 const int* __restrict__ ptq,
                                                 int* __restrict__ qg2, int* __restrict__ gq) {
  int e = blockIdx.x * 256 + threadIdx.x;
  int n = e >> 9;
  int q = qidx[e];
  int s = seq_sort[q];
  int i = (e & 511) - qoffA[n * KL + s];
  int gpos = ptq[s] * 16 + boff[n * KL + s] + i;
  qg2[gpos] = q;
  gq[q] = gpos;
}

// zero the label-tail pad rows of Qsw (deterministic each launch)
__global__ __launch_bounds__(256) void qzero_kernel(const int* __restrict__ ptq,
                                                    const int* __restrict__ qtot,
                                                    __bf16* __restrict__ Qsw) {
  int s = blockIdx.x;
  int b0 = ptq[s] * 16 + qtot[s];
  int b1 = ptq[s + 1] * 16;
  bf8 z;
#pragma unroll
  for (int j = 0; j < 8; ++j) z[j] = (__bf16)0.f;
  for (int r = b0; r < b1; ++r)
    for (int e8 = threadIdx.x; e8 < 128; e8 += 256)
      *(bf8*)&Qsw[(size_t)r * 1024 + e8 * 8] = z;
}

// Ksw[pt][ks][lane][8] = K[pt*16 + (lane&15)][ks*32 + (lane>>4)*8 + i] (bf16; pad rows zero)
__global__ __launch_bounds__(256) void kswb_kernel(const float* __restrict__ wk,
                                                   const int* __restrict__ pridx,
                                                   const int* __restrict__ pbTot,
                                                   __bf16* __restrict__ Ksw) {
  int pt = blockIdx.x;
  if (pt * 16 >= pbTot[0]) return;
  __shared__ __bf16 Tk[16][1040];
  int tid = threadIdx.x;
  int rr = tid >> 4, lt = tid & 15;
  int src = pridx[pt * 16 + rr];
  for (int cc = 0; cc < 16; ++cc) {
    int i4 = cc * 16 + lt;
    f4 v = {0.f, 0.f, 0.f, 0.f};
    if (src >= 0) v = ((const f4*)(wk + (size_t)src * Hh))[i4];
    bf4 o = {(__bf16)v[0], (__bf16)v[1], (__bf16)v[2], (__bf16)v[3]};
    *(bf4*)&Tk[rr][i4 * 4] = o;
  }
  __syncthreads();
#pragma unroll
  for (int i = 0; i < 8; ++i) {
    int f = tid + 256 * i;
    int ks = f >> 6, ln = f & 63;
    int c2 = ln & 15, rg2 = ln >> 4;
    bf8 o = *(const bf8*)&Tk[c2][ks * 32 + rg2 * 8];
    *(bf8*)&Ksw[(size_t)pt * 16384 + (size_t)f * 8] = o;
  }
}

// Vsw[pblk][ff][lane][8] = V^T[ff*16 + (lane&15)][pblk*32 + (lane>>4)*8 + i]
__global__ __launch_bounds__(256) void vswb_kernel(const float* __restrict__ wv_,
                                                   const int* __restrict__ pridx,
                                                   const int* __restrict__ pbTot,
                                                   __bf16* __restrict__ Vsw) {
  int pblk = blockIdx.x;
  if (pblk * 32 >= pbTot[0]) return;
  __shared__ __bf16 Tv[32][528];
  int tid = threadIdx.x;
  int rr = tid >> 3, lt = tid & 7;
  int src = pridx[pblk * 32 + rr];
  for (int cc = 0; cc < 16; ++cc) {
    int i4 = cc * 8 + lt;
    f4 v = {0.f, 0.f, 0.f, 0.f};
    if (src >= 0) v = ((const f4*)(wv_ + (size_t)src * D_EMB))[i4];
    bf4 o = {(__bf16)v[0], (__bf16)v[1], (__bf16)v[2], (__bf16)v[3]};
    *(bf4*)&Tv[rr][i4 * 4] = o;
  }
  __syncthreads();
#pragma unroll
  for (int i = 0; i < 8; ++i) {
    int f = tid + 256 * i;
    int ff = f >> 6, ln = f & 63;
    int c2 = ln & 15, rg2 = ln >> 4;
    bf8 o;
#pragma unroll
    for (int j = 0; j < 8; ++j) o[j] = Tv[rg2 * 8 + j][ff * 16 + c2];
    *(bf8*)&Vsw[(size_t)pblk * 16384 + (size_t)f * 8] = o;
  }
}

// ---------------- RMSNorm of input: inb[j] = bf16(input[j]); Qsw row gq[bw[j]] ----------------
__global__ __launch_bounds__(256) void rms_in_kernel(const float* __restrict__ input,
                                                     const int* __restrict__ bw,
                                                     const int* __restrict__ gq,
                                                     const float* __restrict__ wn,
                                                     __bf16* __restrict__ Qsw,
                                                     __bf16* __restrict__ inb) {
  __shared__ __align__(16) __bf16 rowbuf[4][1024];
  int wv = threadIdx.x >> 6, lane = threadIdx.x & 63;
  int j = blockIdx.x * 4 + wv;
  const f4* src = (const f4*)(input + (size_t)j * Hh);
  f4 v[4];
  float ss = 0.f;
#pragma unroll
  for (int c = 0; c < 4; ++c) {
    v[c] = src[c * 64 + lane];
    ss += v[c][0] * v[c][0] + v[c][1] * v[c][1] + v[c][2] * v[c][2] + v[c][3] * v[c][3];
  }
#pragma unroll
  for (int off = 32; off; off >>= 1) ss += __shfl_xor(ss, off);
  float sc = rsqrtf(ss * (1.f / Hh) + 1e-6f);
  bf4* dstI = (bf4*)(inb + (size_t)j * Hh);
#pragma unroll
  for (int c = 0; c < 4; ++c) {
    bf4 o = {(__bf16)v[c][0], (__bf16)v[c][1], (__bf16)v[c][2], (__bf16)v[c][3]};
    dstI[c * 64 + lane] = o;
  }
  const f4* w4 = (const f4*)wn;
#pragma unroll
  for (int c = 0; c < 4; ++c) {
    f4 w = w4[c * 64 + lane];
    bf4 o = {(__bf16)(v[c][0] * sc * w[0]), (__bf16)(v[c][1] * sc * w[1]),
             (__bf16)(v[c][2] * sc * w[2]), (__bf16)(v[c][3] * sc * w[3])};
    *(bf4*)&rowbuf[wv][(c * 64 + lane) * 4] = o;
  }
  int gpos = gq[bw[j]];
  int qt2 = gpos >> 4, cq = gpos & 15;
#pragma unroll
  for (int h = 0; h < 2; ++h) {
    int k_ = lane + h * 64;
    int ks = k_ >> 2, rg2 = k_ & 3;
    bf8 o = *(const bf8*)&rowbuf[wv][ks * 32 + rg2 * 8];
    *(bf8*)(Qsw + (size_t)qt2 * 16384 + ks * 512 + (cq + 16 * rg2) * 8) = o;
  }
}

// ---------------- wave-per-task attention, XCD label affinity ----------------
__global__ __launch_bounds__(256, 2) void attn6_kernel(const __bf16* __restrict__ Qsw,
                                                       const __bf16* __restrict__ Ksw,
                                                       const __bf16* __restrict__ Vsw,
                                                       const int* __restrict__ qg2,
                                                       const int* __restrict__ qtot,
                                                       const int* __restrict__ ptq,
                                                       const int* __restrict__ taskS,
                                                       const int* __restrict__ taskT,
                                                       const int* __restrict__ xoff,
                                                       const int* __restrict__ xcnt,
                                                       const int* __restrict__ pb,
                                                       const int* __restrict__ loP,
                                                       const int* __restrict__ hiP,
                                                       const int* __restrict__ fw,
                                                       __bf16* __restrict__ comb) {
  __shared__ __align__(16) __bf16 owb[4][16][528];
  int wv = threadIdx.x >> 6, lane = threadIdx.x & 63;
  int x = blockIdx.x & 7;
  int cntx = xcnt[x], offx = xoff[x];
  int c = lane & 15, rg = lane >> 4;
  int sl_a = c + ((rg & 1) << 5);
  int sl_b = sl_a + 16;
  bool hiKt = (rg & 2) != 0;

  for (int slot = (blockIdx.x >> 3) * 4 + wv; slot < cntx; slot += 64 * 4) {
    int t = offx + slot;
    int s = taskS[t], tl = taskT[t];
    int qtp = ptq[s] + tl;
    int qcnt = min(16, qtot[s] - tl * 16);
    bool qv = c < qcnt;
    int q_l = qg2[qtp * 16 + (qv ? c : 0)];
    int n_l = q_l >> 9;
    int lo_l = qv ? loP[n_l * KL + s] : 0x7fffffff;
    int hi_l = qv ? hiP[n_l * KL + s] : 0;
    int tlo = lo_l, thi = hi_l;
#pragma unroll
    for (int off = 1; off < 64; off <<= 1) {
      tlo = min(tlo, __shfl_xor(tlo, off));
      thi = max(thi, __shfl_xor(thi, off));
    }
    if (tlo >= thi) continue;
    int pbs = pb[s];
    const __bf16* Qb = Qsw + (size_t)qtp * 16384 + lane * 8;

    float m = -1e30f, lsum = 0.f;
    f32x4 acc[32];
    f32x4 zero = {0.f, 0.f, 0.f, 0.f};
#pragma unroll
    for (int ff = 0; ff < 32; ++ff) acc[ff] = zero;

    int p0beg = pbs + ((tlo - pbs) & ~63);
    for (int p0 = p0beg; p0 < thi; p0 += 64) {
      const __bf16* Kb = Ksw + (size_t)(p0 >> 4) * 16384 + lane * 8;
      f32x4 sN[4];
#pragma unroll
      for (int kt = 0; kt < 4; ++kt) sN[kt] = zero;
#pragma unroll
      for (int ks = 0; ks < 32; ++ks) {
        bf8 qf = *(const bf8*)(Qb + ks * 512);
#pragma unroll
        for (int kt = 0; kt < 4; ++kt) {
          bf8 kf = *(const bf8*)(Kb + kt * 16384 + ks * 512);
          sN[kt] = __builtin_amdgcn_mfma_f32_16x16x32_bf16(kf, qf, sN[kt], 0, 0, 0);
        }
      }
      float smax = -1e30f;
#pragma unroll
      for (int kt = 0; kt < 4; ++kt)
#pragma unroll
        for (int r = 0; r < 4; ++r) {
          int kv = p0 + kt * 16 + rg * 4 + r;
          float sv = (kv >= lo_l && kv < hi_l) ? sN[kt][r] : -1e30f;
          sN[kt][r] = sv;
          smax = fmaxf(smax, sv);
        }
      smax = fmaxf(smax, __shfl_xor(smax, 16));
      smax = fmaxf(smax, __shfl_xor(smax, 32));
      float mn = fmaxf(m, smax);
      float scl = __expf(m - mn);
      float sum = 0.f;
#pragma unroll
      for (int kt = 0; kt < 4; ++kt)
#pragma unroll
        for (int r = 0; r < 4; ++r) {
          float pv = __expf(sN[kt][r] - mn);
          sN[kt][r] = pv;
          sum += pv;
        }
      sum += __shfl_xor(sum, 16);
      sum += __shfl_xor(sum, 32);
      lsum = lsum * scl + sum;
      m = mn;
#pragma unroll
      for (int ff = 0; ff < 32; ++ff) acc[ff] = acc[ff] * scl;

      bf8 pbh[2];
#pragma unroll
      for (int h = 0; h < 2; ++h) {
        float e[8];
#pragma unroll
        for (int r = 0; r < 4; ++r) {
          float a0 = __shfl(sN[2 * h][r], sl_a);
          float a1 = __shfl(sN[2 * h + 1][r], sl_a);
          e[r] = hiKt ? a1 : a0;
          float b0 = __shfl(sN[2 * h][r], sl_b);
          float b1 = __shfl(sN[2 * h + 1][r], sl_b);
          e[4 + r] = hiKt ? b1 : b0;
        }
        bf8 pbv;
#pragma unroll
        for (int i = 0; i < 8; ++i) pbv[i] = (__bf16)e[i];
        pbh[h] = pbv;
      }
      const __bf16* Vb = Vsw + (size_t)(p0 >> 5) * 16384 + lane * 8;
#pragma unroll
      for (int ff = 0; ff < 32; ++ff) {
        bf8 v0 = *(const bf8*)(Vb + ff * 512);
        bf8 v1 = *(const bf8*)(Vb + 16384 + ff * 512);
        acc[ff] = __builtin_amdgcn_mfma_f32_16x16x32_bf16(v0, pbh[0], acc[ff], 0, 0, 0);
        acc[ff] = __builtin_amdgcn_mfma_f32_16x16x32_bf16(v1, pbh[1], acc[ff], 0, 0, 0);
      }
    }

    float inv = 1.f / lsum;
#pragma unroll
    for (int ff = 0; ff < 32; ++ff) {
      bf4 o;
#pragma unroll
      for (int r = 0; r < 4; ++r) o[r] = (__bf16)(acc[ff][r] * inv);
      *(bf4*)&owb[wv][c][ff * 16 + rg * 4] = o;
    }
    int qsel = lane >> 2;
    bool vq = qsel < qcnt;
    size_t ob = 0;
    if (vq) ob = (size_t)fw[qg2[qtp * 16 + qsel]] * D_EMB + (lane & 3) * 8;
#pragma unroll
    for (int it = 0; it < 16; ++it) {
      bf8 o = *(const bf8*)&owb[wv][lane >> 2][(lane & 3) * 8 + it * 32];
      if (vq) *(bf8*)(comb + ob + (size_t)it * 32) = o;
    }
  }
}

// ---------------- 256x256 ring-pipelined GEMM, ONE barrier per 32-MFMA tile ----------------
// BK=32, 4-buffer ring (stage t+3 while computing t), counted vmcnt(8) with
// correct tail stepping 8->4->0, XOR slot swizzle (both sides), setprio, XCD chunking.
template <bool OUT_BF16>
__global__ __launch_bounds__(512, 2) void gemm9(const __bf16* __restrict__ x0, int k0,
                                                const __bf16* __restrict__ x1, int k1,
                                                const __bf16* __restrict__ w,
                                                void* __restrict__ outp, int Mt, int Nt) {
  __shared__ __align__(16) __bf16 lds[4][2][256 * 32];
  const int nwg = Mt * Nt;
  const int bid = blockIdx.x;
  const int swz = (bid % NXCD) * (nwg / NXCD) + bid / NXCD;
  const int m0 = (swz / Nt) * 256, n0 = (swz % Nt) * 256;
  const int K = k0 + k1;
  const int NT = K >> 5;
  const int N = Nt * 256;
  const int tid = threadIdx.x, lane = tid & 63, wvi = tid >> 6;
  const int wr = wvi >> 2, wc = wvi & 3;
  const int srow = tid >> 2;
  const int spb = (tid & 3) * 16;
  const int c = lane & 15, rg = lane >> 4;
  const int fa_off = c * 64 + ((rg ^ ((c >> 1) & 3)) << 4);

  auto stage = [&](int t) {
    int kg = t * 32;
    const __bf16* xs;
    int ld, kk;
    if (kg < k0) { xs = x0; ld = k0; kk = kg; }
    else         { xs = x1; ld = k1; kk = kg - k0; }
    int b = t & 3;
#pragma unroll
    for (int j = 0; j < 2; ++j) {
      int r = j * 128 + srow;
      int lcol = (spb ^ (((r >> 1) & 3) << 4)) >> 1;
      gl_lds16(xs + (size_t)(m0 + r) * ld + kk + lcol,
               (void*)((char*)&lds[b][0][0] + r * 64 + spb));
      gl_lds16(w + (size_t)(n0 + r) * K + kg + lcol,
               (void*)((char*)&lds[b][1][0] + r * 64 + spb));
    }
  };

  f32x4 acc[8][4];
  f32x4 zero = {0.f, 0.f, 0.f, 0.f};
#pragma unroll
  for (int a = 0; a < 8; ++a)
#pragma unroll
    for (int bnx = 0; bnx < 4; ++bnx) acc[a][bnx] = zero;

  auto compute = [&](int t) {
    const char* Ab = (const char*)&lds[t & 3][0][0];
    const char* Bb = (const char*)&lds[t & 3][1][0];
    bf8 afr[8], bfr[4];
#pragma unroll
    for (int fi = 0; fi < 8; ++fi)
      afr[fi] = *(const bf8*)(Ab + (wr * 128 + fi * 16) * 64 + fa_off);
#pragma unroll
    for (int ni = 0; ni < 4; ++ni)
      bfr[ni] = *(const bf8*)(Bb + (wc * 64 + ni * 16) * 64 + fa_off);
    __builtin_amdgcn_s_setprio(1);
#pragma unroll
    for (int fi = 0; fi < 8; ++fi)
#pragma unroll
      for (int ni = 0; ni < 4; ++ni)
        acc[fi][ni] = __builtin_amdgcn_mfma_f32_16x16x32_bf16(afr[fi], bfr[ni], acc[fi][ni], 0, 0, 0);
    __builtin_amdgcn_s_setprio(0);
  };

  // prologue: stage tiles 0,1,2; ensure tile 0 landed (<=8 outstanding)
  stage(0); stage(1); stage(2);
  asm volatile("s_waitcnt vmcnt(8)" ::: "memory");
  __builtin_amdgcn_s_barrier();

  for (int t = 0; t < NT - 3; ++t) {
    stage(t + 3);
    compute(t);
    asm volatile("s_waitcnt vmcnt(8)" ::: "memory");
    __builtin_amdgcn_s_barrier();
  }
  // tail: no more staging; drain 4 -> 0
  compute(NT - 3);
  asm volatile("s_waitcnt vmcnt(4)" ::: "memory");
  __builtin_amdgcn_s_barrier();
  compute(NT - 2);
  asm volatile("s_waitcnt vmcnt(0)" ::: "memory");
  __builtin_amdgcn_s_barrier();
  compute(NT - 1);

  const int r0 = (lane >> 4) * 4, cc = lane & 15;
#pragma unroll
  for (int mi = 0; mi < 8; ++mi) {
    int rowb = m0 + wr * 128 + mi * 16 + r0;
#pragma unroll
    for (int ni = 0; ni < 4; ++ni) {
      int col = n0 + wc * 64 + ni * 16 + cc;
#pragma unroll
      for (int r = 0; r < 4; ++r) {
        float v = acc[mi][ni][r];
        if (OUT_BF16)
          ((__bf16*)outp)[(size_t)(rowb + r) * N + col] = (__bf16)v;
        else
          ((float*)outp)[(size_t)(rowb + r) * N + col] = v;
      }
    }
  }
}

// ---------------- in-place RMSNorm of up ----------------
__global__ __launch_bounds__(256) void rms_up_kernel(__bf16* __restrict__ up,
                                                     const float* __restrict__ wn) {
  int wv = threadIdx.x >> 6, lane = threadIdx.x & 63;
  size_t j = (size_t)blockIdx.x * 4 + wv;
  bf8* row = (bf8*)(up + j * D_UP);
  bf8 v[4];
  float ss = 0.f;
#pragma unroll
  for (int c = 0; c < 4; ++c) {
    v[c] = row[c * 64 + lane];
#pragma unroll
    for (int i = 0; i < 8; ++i) { float f = (float)v[c][i]; ss += f * f; }
  }
#pragma unroll
  for (int off = 32; off; off >>= 1) ss += __shfl_xor(ss, off);
  float sc = rsqrtf(ss * (1.f / D_UP) + 1e-6f);
#pragma unroll
  for (int c = 0; c < 4; ++c) {
    int ebase = (c * 64 + lane) * 8;
    f4 wa = *(const f4*)(wn + ebase);
    f4 wb = *(const f4*)(wn + ebase + 4);
    bf8 o;
#pragma unroll
    for (int i = 0; i < 4; ++i) o[i] = (__bf16)((float)v[c][i] * sc * wa[i]);
#pragma unroll
    for (int i = 0; i < 4; ++i) o[4 + i] = (__bf16)((float)v[c][4 + i] * sc * wb[i]);
    row[c * 64 + lane] = o;
  }
}

// ---------------- launch ----------------
extern "C" void kernel_launch(void* const* d_in, const int* in_sizes, int n_in, void* d_out,
                              int out_size, void* d_ws, size_t ws_size, hipStream_t stream) {
  const float* input = (const float*)d_in[0];
  const int* fw = (const int*)d_in[1];
  const int* bw = (const int*)d_in[2];
  const int* seq_sort = (const int*)d_in[3];
  const int* keep_cols = (const int*)d_in[4];
  const int* emb_alloc = (const int*)d_in[5];
  const int* starts = (const int*)d_in[6];
  const int* ends = (const int*)d_in[7];
  const float* w_k = (const float*)d_in[9];
  const float* w_v = (const float*)d_in[10];
  const float* w_up = (const float*)d_in[11];
  const float* w_mix = (const float*)d_in[12];
  const float* w_nin = (const float*)d_in[13];
  const float* w_nout = (const float*)d_in[14];

  char* p = (char*)d_ws;
  auto take = [&](size_t b) {
    void* r = (void*)p;
    p += (b + 255) & ~(size_t)255;
    return r;
  };
  // region A: persistent through the whole pipeline
  __bf16* inb = (__bf16*)take((size_t)BT * Hh * 2);
  __bf16* comb = (__bf16*)take((size_t)BT * D_EMB * 2);
  __bf16* wupB = (__bf16*)take((size_t)D_UP * D_EMB * 2);
  __bf16* wmixB = (__bf16*)take((size_t)Hh * (D_UP + Hh) * 2);
  // region B: attention-phase only; `up` aliases it afterwards
  char* pB = p;
  __bf16* Ksw = (__bf16*)take((size_t)PMMAX * 1024 * 2);
  __bf16* Vsw = (__bf16*)take((size_t)PMMAX * 512 * 2);
  __bf16* Qsw = (__bf16*)take((size_t)QROWMAX * 1024 * 2);
  int* la = (int*)take(Mm * 4);
  int* stA = (int*)take(NB * 4);
  int* enA = (int*)take(NB * 4);
  int* goff = (int*)take((KL + 1) * 4);
  int* gk = (int*)take(Mm * 4);
  int* ridx = (int*)take(Mm * 4);
  int* pridx = (int*)take(PMMAX * 4);
  int* loA = (int*)take(NB * KL * 4);
  int* hiA = (int*)take(NB * KL * 4);
  int* qidx = (int*)take(BT * 4);
  int* qoffA = (int*)take(NB * KL * 4);
  int* qcntA = (int*)take(NB * KL * 4);
  int* boff = (int*)take(NB * KL * 4);
  int* qtot = (int*)take(KL * 4);
  int* ptq = (int*)take((KL + 1) * 4);
  int* pb = (int*)take(KL * 4);
  int* taskS = (int*)take(MAXT * 4);
  int* taskT = (int*)take(MAXT * 4);
  int* xoff = (int*)take(NXCD * 4);
  int* xcnt = (int*)take(NXCD * 4);
  int* pbTot = (int*)take(4);
  int* qg2 = (int*)take(QROWMAX * 4);
  int* gq = (int*)take(BT * 4);
  // up aliases region B (dead after attn6); regenerated every launch
  __bf16* up = (__bf16*)pB;

  // prep
  conv_bf16_kernel<<<(D_UP * D_EMB / 4 + 255) / 256, 256, 0, stream>>>(w_up, wupB, D_UP * D_EMB / 4);
  conv_bf16_kernel<<<(Hh * (D_UP + Hh) / 4 + 255) / 256, 256, 0, stream>>>(w_mix, wmixB,
                                                                           Hh * (D_UP + Hh) / 4);
  la_kernel<<<Mm / 256, 256, 0, stream>>>(keep_cols, emb_alloc, la, Mm);
  range_kernel<<<NB, 256, 0, stream>>>(starts, ends, stA, enA);
  hist_kernel<<<1, 256, 0, stream>>>(la, goff);
  qsort_kernel<<<NB, 256, 0, stream>>>(seq_sort, qidx, qoffA, qcntA);
  place_kernel<<<KL, 256, 0, stream>>>(la, keep_cols, goff, gk, ridx);
  qmeta_kernel<<<1, 256, 0, stream>>>(qcntA, goff, boff, qtot, ptq, pb, taskS, taskT, xoff, xcnt,
                                      pbTot);
  pridx_kernel<<<KL, 256, 0, stream>>>(goff, pb, ridx, pridx);
  lohi_kernel<<<(NB * KL + 255) / 256, 256, 0, stream>>>(gk, goff, pb, stA, enA, loA, hiA);
  gq_kernel<<<BT / 256, 256, 0, stream>>>(qidx, qoffA, seq_sort, boff, ptq, qg2, gq);
  qzero_kernel<<<KL, 256, 0, stream>>>(ptq, qtot, Qsw);
  kswb_kernel<<<PMMAX / 16, 256, 0, stream>>>(w_k, pridx, pbTot, Ksw);
  vswb_kernel<<<PMMAX / 32, 256, 0, stream>>>(w_v, pridx, pbTot, Vsw);

  // pipeline
  rms_in_kernel<<<BT / 4, 256, 0, stream>>>(input, bw, gq, w_nin, Qsw, inb);
  attn6_kernel<<<512, 256, 0, stream>>>(Qsw, Ksw, Vsw, qg2, qtot, ptq, taskS, taskT, xoff, xcnt,
                                        pb, loA, hiA, fw, comb);
  gemm9<true><<<BT / 256 * (D_UP / 256), 512, 0, stream>>>(comb, D_EMB, (const __bf16*)nullptr, 0,
                                                           wupB, (void*)up, BT / 256, D_UP / 256);
  rms_up_kernel<<<BT / 4, 256, 0, stream>>>(up, w_nout);
  gemm9<false><<<BT / 256 * (Hh / 256), 512, 0, stream>>>(up, D_UP, inb, Hh, wmixB, d_out,
                                                          BT / 256, Hh / 256);
}